// Round 1
// 262.727 us; speedup vs baseline: 1.0719x; 1.0719x over previous
//
#include <hip/hip_runtime.h>
#include <hip/hip_bf16.h>

#define C   64
#define Hh  128
#define Ww  128
#define HW  16384

typedef __attribute__((ext_vector_type(8))) short bf16x8;
typedef __attribute__((ext_vector_type(4))) float f32x4;

__device__ __forceinline__ unsigned short f2bf(float f) {
    unsigned u = __builtin_bit_cast(unsigned, f);
    unsigned r = (u + 0x7fff + ((u >> 16) & 1)) >> 16;
    return (unsigned short)r;
}

// ---------------------------------------------------------------------------
// Prep: fold BN scale into 1x1 proj weights (bf16), compute shifts, and pack
// conv weights to wp[ch2][tap9][co64][ci32] bf16 for each conv half.
// ---------------------------------------------------------------------------
__global__ __launch_bounds__(256) void prep_kernel(
    const float* __restrict__ pu_w, const float* __restrict__ pu_g,
    const float* __restrict__ pu_b, const float* __restrict__ pu_m,
    const float* __restrict__ pu_v,
    const float* __restrict__ pv_w, const float* __restrict__ pv_g,
    const float* __restrict__ pv_b, const float* __restrict__ pv_m,
    const float* __restrict__ pv_v,
    const float* __restrict__ conv_w,
    short* __restrict__ pwu, short* __restrict__ pwv,
    short* __restrict__ wpu, short* __restrict__ wpv,
    float* __restrict__ shu, float* __restrict__ shv)
{
    const int idx = blockIdx.x * 256 + threadIdx.x;
    if (idx < 8192) {                       // proj weights, scale-folded
        const int c  = idx >> 12;
        const int r  = idx & 4095;
        const int co = r >> 6, ci = r & 63;
        const float* w = c ? pv_w : pu_w;
        const float* g = c ? pv_g : pu_g;
        const float* vv = c ? pv_v : pu_v;
        const float scale = g[co] * rsqrtf(vv[co] + 1e-5f);
        (c ? pwv : pwu)[r] = (short)f2bf(w[co * 64 + ci] * scale);
    } else if (idx < 81920) {               // conv weights repack
        const int flat = idx - 8192;
        const int c  = flat / 36864;
        const int r  = flat % 36864;
        const int ch  = r / 18432;
        const int r2  = r % 18432;
        const int tap = r2 / 2048;
        const int r3  = r2 & 2047;
        const int co = r3 >> 5, ci = r3 & 31;
        const float src = conv_w[(size_t)(co * 128 + c * 64 + ch * 32 + ci) * 9 + tap];
        (c ? wpv : wpu)[((ch * 9 + tap) * 64 + co) * 32 + ci] = (short)f2bf(src);
    } else if (idx < 82048) {               // shifts
        const int r  = idx - 81920;
        const int c  = r >> 6, co = r & 63;
        const float* g = c ? pv_g : pu_g;
        const float* b = c ? pv_b : pu_b;
        const float* m = c ? pv_m : pu_m;
        const float* vv = c ? pv_v : pu_v;
        const float scale = g[co] * rsqrtf(vv[co] + 1e-5f);
        (c ? shv : shu)[co] = b[co] - m[co] * scale;
    }
}

// ---------------------------------------------------------------------------
// Proj: y[img][pix][co] = bf16(relu( sum_ci x[img][ci][pix]*pw[co][ci] + shift[co] ))
// MFMA 16x16x32 bf16, M=pix, N=co, K=64. Block: 256 px, 4 waves x 64 px.
// Handles both u (blockIdx.y<8) and v (>=8) in one launch.
// ---------------------------------------------------------------------------
__global__ __launch_bounds__(256) void proj_mfma(
    const float* __restrict__ xu, const float* __restrict__ xv,
    const short* __restrict__ pwu_, const short* __restrict__ pwv_,
    const float* __restrict__ shu_, const float* __restrict__ shv_,
    short* __restrict__ yu, short* __restrict__ yv)
{
    __shared__ short xs[256 * 72];      // [pix][64ci + 8 pad] bf16
    __shared__ short pwl[64 * 72];      // [co][64ci + 8 pad]
    __shared__ float ssh[64];

    const int img16 = blockIdx.y;
    const int sel   = img16 >> 3;
    const int img   = img16 & 7;
    const float* x      = sel ? xv   : xu;
    const short* pw     = sel ? pwv_ : pwu_;
    const float* shiftg = sel ? shv_ : shu_;
    short* y            = sel ? yv   : yu;

    const int pix0 = blockIdx.x * 256;
    const int tid  = threadIdx.x;

    // ---- stage x: transpose [ci][pix] fp32 -> [pix][ci] bf16 ----
    const float* xi = x + (size_t)img * C * HW + pix0 + tid;
#pragma unroll 8
    for (int c2 = 0; c2 < 32; ++c2) {
        const float a = xi[(size_t)(2 * c2) * HW];
        const float b = xi[(size_t)(2 * c2 + 1) * HW];
        const int packed = (int)f2bf(a) | ((int)f2bf(b) << 16);
        *(int*)(&xs[tid * 72 + c2 * 2]) = packed;
    }
    // ---- stage weights (16B chunks) + shift ----
#pragma unroll
    for (int it = 0; it < 2; ++it) {
        const int idx = tid + it * 256;      // 512 chunks
        const int oct = idx & 7, co = idx >> 3;
        *(int4*)(&pwl[co * 72 + oct * 8]) = *(const int4*)(&pw[co * 64 + oct * 8]);
    }
    if (tid < 64) ssh[tid] = shiftg[tid];
    __syncthreads();

    const int wq = tid >> 6;
    const int lane = tid & 63;
    const int lx = lane & 15;
    const int q  = lane >> 4;

    f32x4 acc[4][4];
#pragma unroll
    for (int mt = 0; mt < 4; ++mt)
#pragma unroll
        for (int nt = 0; nt < 4; ++nt) acc[mt][nt] = (f32x4){0.f, 0.f, 0.f, 0.f};

#pragma unroll
    for (int kc = 0; kc < 2; ++kc) {
        bf16x8 a[4], b[4];
#pragma unroll
        for (int mt = 0; mt < 4; ++mt)
            a[mt] = *(const bf16x8*)&xs[((wq * 4 + mt) * 16 + lx) * 72 + kc * 32 + q * 8];
#pragma unroll
        for (int nt = 0; nt < 4; ++nt)
            b[nt] = *(const bf16x8*)&pwl[(nt * 16 + lx) * 72 + kc * 32 + q * 8];
#pragma unroll
        for (int mt = 0; mt < 4; ++mt)
#pragma unroll
            for (int nt = 0; nt < 4; ++nt)
                acc[mt][nt] = __builtin_amdgcn_mfma_f32_16x16x32_bf16(a[mt], b[nt], acc[mt][nt], 0, 0, 0);
    }

    // ---- epilogue: +shift, relu, bf16, store [pix][co] ----
    short* yo = y + ((size_t)img * HW + pix0) * C;
#pragma unroll
    for (int mt = 0; mt < 4; ++mt)
#pragma unroll
        for (int nt = 0; nt < 4; ++nt)
#pragma unroll
            for (int r = 0; r < 4; ++r) {
                const int pixl = (wq * 4 + mt) * 16 + q * 4 + r;
                const int co = nt * 16 + lx;
                float vv = acc[mt][nt][r] + ssh[co];
                vv = fmaxf(vv, 0.f);
                yo[(size_t)pixl * C + co] = (short)f2bf(vv);
            }
}

// ---------------------------------------------------------------------------
// Conv 3x3 pad=1 via implicit GEMM MFMA 16x16x32 bf16.
// M=co(64), N=pixels. Block: 32w x 8h = 256 px, 4 waves, each 64co x 64px.
// K = 2 cihalf x 9 tap x 32ci. Activations act[img][pix][ci] bf16.
// Weights wp[ch][tap][co][32ci] bf16; ALL 9 taps of one ch staged at once
// (46 KiB) so each ch-half is a single 144-MFMA run between 2 barriers.
// FUSED=false: write ou[img][co][hw] fp32.
// FUSED=true : cross-add epilogue — for sx=0..3 read ou[b*4+sx] tile, add
//              acc (=ov tile) + bias, nontemporal-store out[b][sx][sy].
// ---------------------------------------------------------------------------
template<bool FUSED>
__global__ __launch_bounds__(256, 2) void conv_core(
    const short* __restrict__ act, const short* __restrict__ wp,
    const float* __restrict__ ou, const float* __restrict__ bias,
    float* __restrict__ outp)
{
    __shared__ short xs[340 * 40];        // [10h x 34w][32ci + 8 pad]  27.2 KB
    __shared__ short wsm[9 * 64 * 40];    // [tap9][co][32ci + 8 pad]   46.1 KB
    __shared__ float sbias[64];

    const int img = blockIdx.y;
    const int tx = blockIdx.x & 3, ty = blockIdx.x >> 2;
    const int h0 = ty * 8, w0 = tx * 32;
    const int tid = threadIdx.x;
    const int wq = tid >> 6;
    const int lane = tid & 63;
    const int lx = lane & 15;
    const int q8 = (lane >> 4) * 8;

    if (FUSED && tid < 64) sbias[tid] = bias[tid];

    f32x4 acc[4][4];
#pragma unroll
    for (int mt = 0; mt < 4; ++mt)
#pragma unroll
        for (int nt = 0; nt < 4; ++nt) acc[mt][nt] = (f32x4){0.f, 0.f, 0.f, 0.f};

    const short* ub = act + (size_t)img * HW * C;

    for (int ch = 0; ch < 2; ++ch) {
        __syncthreads();
        // ---- stage activations halo: 10 x 34 cells x 4 octs of 8 ci ----
        for (int idx = tid; idx < 1360; idx += 256) {
            const int oct = idx & 3;
            const int pcell = idx >> 2;
            const int h = pcell / 34, w = pcell - h * 34;
            const int gh = h0 - 1 + h, gw = w0 - 1 + w;
            int4 v = {0, 0, 0, 0};
            if (gh >= 0 && gh < Hh && gw >= 0 && gw < Ww)
                v = *(const int4*)&ub[(size_t)(gh * Ww + gw) * C + ch * 32 + oct * 8];
            *(int4*)(&xs[pcell * 40 + oct * 8]) = v;
        }
        // ---- stage ALL 9 taps of weights for this ch ----
        for (int idx = tid; idx < 2304; idx += 256) {
            const int oct = idx & 3;
            const int co = (idx >> 2) & 63;
            const int tl = idx >> 8;
            *(int4*)(&wsm[(tl * 64 + co) * 40 + oct * 8]) =
                *(const int4*)&wp[(((ch * 9 + tl) * 64) + co) * 32 + oct * 8];
        }
        __syncthreads();
        // ---- compute: one straight 9-tap, 144-MFMA run ----
#pragma unroll
        for (int t = 0; t < 9; ++t) {
            const int ky = t / 3;
            const int kx = t - ky * 3;
            bf16x8 a[4], b[4];
#pragma unroll
            for (int mt = 0; mt < 4; ++mt)
                a[mt] = *(const bf16x8*)&wsm[(t * 64 + mt * 16 + lx) * 40 + q8];
#pragma unroll
            for (int nt = 0; nt < 4; ++nt) {
                const int cell = (2 * wq + (nt >> 1) + ky) * 34 + (nt & 1) * 16 + lx + kx;
                b[nt] = *(const bf16x8*)&xs[cell * 40 + q8];
            }
#pragma unroll
            for (int mt = 0; mt < 4; ++mt)
#pragma unroll
                for (int nt = 0; nt < 4; ++nt)
                    acc[mt][nt] = __builtin_amdgcn_mfma_f32_16x16x32_bf16(a[mt], b[nt], acc[mt][nt], 0, 0, 0);
        }
    }

    const int qq = lane >> 4;
    if (!FUSED) {
        // ---- store ou[img][co][h][w] fp32 (kept cache-resident for reuse) ----
        float* ob = outp + (size_t)img * C * HW;
#pragma unroll
        for (int mt = 0; mt < 4; ++mt)
#pragma unroll
            for (int nt = 0; nt < 4; ++nt)
#pragma unroll
                for (int r = 0; r < 4; ++r) {
                    const int co = mt * 16 + qq * 4 + r;
                    const int h = h0 + 2 * wq + (nt >> 1);
                    const int w = w0 + (nt & 1) * 16 + lx;
                    ob[(size_t)co * HW + h * Ww + w] = acc[mt][nt][r];
                }
    } else {
        // ---- fused cross-add: acc holds ov tile for img = b*4+sy ----
        const int b  = img >> 2;
        const int sy = img & 3;
        // fold bias into acc once
#pragma unroll
        for (int mt = 0; mt < 4; ++mt)
#pragma unroll
            for (int nt = 0; nt < 4; ++nt)
#pragma unroll
                for (int r = 0; r < 4; ++r)
                    acc[mt][nt][r] += sbias[mt * 16 + qq * 4 + r];

#pragma unroll
        for (int sx = 0; sx < 4; ++sx) {
            const float* oub = ou + (size_t)(b * 4 + sx) * C * HW;
            float* ob = outp + ((size_t)((b * 4 + sx) * 4 + sy)) * C * HW;
#pragma unroll
            for (int mt = 0; mt < 4; ++mt)
#pragma unroll
                for (int nt = 0; nt < 4; ++nt)
#pragma unroll
                    for (int r = 0; r < 4; ++r) {
                        const int co = mt * 16 + qq * 4 + r;
                        const int h = h0 + 2 * wq + (nt >> 1);
                        const int w = w0 + (nt & 1) * 16 + lx;
                        const size_t off = (size_t)co * HW + h * Ww + w;
                        __builtin_nontemporal_store(acc[mt][nt][r] + oub[off], &ob[off]);
                    }
        }
    }
}

// ---------------------------------------------------------------------------
extern "C" void kernel_launch(void* const* d_in, const int* in_sizes, int n_in,
                              void* d_out, int out_size, void* d_ws, size_t ws_size,
                              hipStream_t stream)
{
    const float* u        = (const float*)d_in[0];
    const float* v        = (const float*)d_in[1];
    const float* pu_w     = (const float*)d_in[2];
    const float* pu_gamma = (const float*)d_in[3];
    const float* pu_beta  = (const float*)d_in[4];
    const float* pu_mean  = (const float*)d_in[5];
    const float* pu_var   = (const float*)d_in[6];
    const float* pv_w     = (const float*)d_in[7];
    const float* pv_gamma = (const float*)d_in[8];
    const float* pv_beta  = (const float*)d_in[9];
    const float* pv_mean  = (const float*)d_in[10];
    const float* pv_var   = (const float*)d_in[11];
    const float* conv_w   = (const float*)d_in[12];
    const float* conv_b   = (const float*)d_in[13];
    float* out = (float*)d_out;

    char* ws = (char*)d_ws;
    short* uf  = (short*)(ws);                         // 16,777,216 B
    short* vf  = (short*)(ws + 16777216);              // 16,777,216 B
    float* ou  = (float*)(ws + 33554432);              // 33,554,432 B
    char*  aux = ws + 100663296;
    short* pwu = (short*)(aux);                        // 8192 B
    short* pwv = (short*)(aux + 8192);                 // 8192 B
    short* wpu = (short*)(aux + 16384);                // 73,728 B
    short* wpv = (short*)(aux + 90112);                // 73,728 B
    float* shu = (float*)(aux + 163840);               // 256 B
    float* shv = (float*)(aux + 164096);               // 256 B

    prep_kernel<<<321, 256, 0, stream>>>(pu_w, pu_gamma, pu_beta, pu_mean, pu_var,
                                         pv_w, pv_gamma, pv_beta, pv_mean, pv_var,
                                         conv_w, pwu, pwv, wpu, wpv, shu, shv);

    dim3 gp(64, 16);
    proj_mfma<<<gp, 256, 0, stream>>>(u, v, pwu, pwv, shu, shv, uf, vf);

    dim3 gc(64, 8);
    conv_core<false><<<gc, 256, 0, stream>>>(uf, wpu, nullptr, nullptr, ou);
    conv_core<true ><<<gc, 256, 0, stream>>>(vf, wpv, ou, conv_b, out);
}